// Round 3
// baseline (312.057 us; speedup 1.0000x reference)
//
#include <hip/hip_runtime.h>

#define HH 479
#define WW 639
#define BATCH 8
#define NBLK (40 * 30 * 8)   // 9600 blocks

// Separable moments per (output-row i, window-col c):
//   S1=SUM d^2, Sb=SUM b d^2, Sbb=SUM b^2 d^2, T1=SUM d, Tb=SUM b d  (8 rows)
// Per pixel combine over 8 window-cols with weights {1, a, a^2}.
// Solve: adjugate*rhs (m) in f64 (cancellation-prone), finish in f32.
// Det-free flip: final = -sign(dot(m, xyz)) * m/|m|  (sign(det) cancels in the
// flip case analysis; only measure-zero dot==0 differs).

__device__ __forceinline__ void solve_normal(
    float xx, float xy, float xz, float yy, float yz, float zz,
    float xs, float ys, float zs,
    float a_c, float b_c, float d0,
    float* nx, float* ny, float* nz)
{
    const double EPSV = 1e-6;
    double p = (double)xx + EPSV, q = (double)xy, r = (double)xz;
    double s = (double)yy + EPSV, t = (double)yz, u = (double)zz + EPSV;
    double c00 = s * u - t * t;
    double c01 = r * t - q * u;
    double c02 = q * t - r * s;
    double c11 = p * u - r * r;
    double c12 = q * r - p * t;
    double c22 = p * s - q * q;
    double m0 = c00 * (double)xs + c01 * (double)ys + c02 * (double)zs;
    double m1 = c01 * (double)xs + c11 * (double)ys + c12 * (double)zs;
    double m2 = c02 * (double)xs + c12 * (double)ys + c22 * (double)zs;
    float f0 = (float)m0, f1 = (float)m1, f2 = (float)m2;
    float g = fmaf(f0, a_c, fmaf(f1, b_c, f2));      // sign of dot(n,xyz) up to sign(det)>0 factors
    float inv = rsqrtf(fmaf(f0, f0, fmaf(f1, f1, f2 * f2)));
    if (g > 0.0f) inv = -inv;
    if (!(d0 > 0.0f)) inv = 0.0f;                    // where(depth>0, n, 0)
    *nx = f0 * inv; *ny = f1 * inv; *nz = f2 * inv;
}

__global__ __launch_bounds__(256, 4)
void ppal_main(const float* __restrict__ pred, const float* __restrict__ gt,
               double* __restrict__ acc, unsigned int* __restrict__ cnt,
               float* __restrict__ out)
{
    const int tx = threadIdx.x;        // 0..15
    const int ty = threadIdx.y;        // 0..15
    const int tid = ty * 16 + tx;
    const int j0 = blockIdx.x * 16;
    const int i0 = blockIdx.y * 16;
    const int b  = blockIdx.z;

    const float invFX = 1.0f / 518.857f;
    const float invFY = 1.0f / 519.469f;

    // depth tile rows i0-4..i0+18 (23), cols j0-4..j0+18 (23); stride 24
    __shared__ float sd[2][23 * 24];
    // column sums, entry e=i*24+c: dw0-1={S1,Sb}, dw2-3={Sbb,T1}, dw4=Tb, dw5 pad
    // stride 6 dw: b64 banks 6tx+{0,1} mod 32 cover all 32 -> conflict-free
    __shared__ float cs[2][384][6];
    __shared__ float csTb[2][384];

    const float* src0 = pred + (size_t)b * (HH * WW);
    const float* src1 = gt   + (size_t)b * (HH * WW);
    for (int idx = tid; idx < 23 * 24; idx += 256) {
        int lr = idx / 24, lc = idx - lr * 24;
        int r = i0 - 4 + lr, c = j0 - 4 + lc;
        bool ok = (lc < 23) && (r >= 0) && (r < HH) && (c >= 0) && (c < WW);
        int off = r * WW + c;
        sd[0][idx] = ok ? src0[off] : 0.0f;
        sd[1][idx] = ok ? src1[off] : 0.0f;
    }
    __syncthreads();

    // ---- stage 1: row reductions; tasks t: i=t/24, c=t%24 (consecutive LDS) ----
    for (int t = tid; t < 384; t += 256) {
        int i = t / 24;
        int c = t - i * 24;
        float S1[2] = {0.f, 0.f}, Sb[2] = {0.f, 0.f}, Sbb[2] = {0.f, 0.f};
        float T1[2] = {0.f, 0.f}, Tb[2] = {0.f, 0.f};
#pragma unroll
        for (int dr = 0; dr < 8; ++dr) {
            float bv = ((float)(i0 + i - 4 + dr) - 239.5f) * invFY;
#pragma unroll
            for (int k = 0; k < 2; ++k) {
                float d  = sd[k][(i + dr) * 24 + c];
                float bd = bv * d;
                T1[k] += d;
                Tb[k] += bd;
                S1[k]  = fmaf(d,  d,  S1[k]);
                Sb[k]  = fmaf(bd, d,  Sb[k]);
                Sbb[k] = fmaf(bd, bd, Sbb[k]);
            }
        }
#pragma unroll
        for (int k = 0; k < 2; ++k) {
            float* e = cs[k][t];
            *(float2*)(e)     = make_float2(S1[k], Sb[k]);
            *(float2*)(e + 2) = make_float2(Sbb[k], T1[k]);
            csTb[k][t] = Tb[k];
        }
    }
    __syncthreads();

    // ---- stage 2: per-pixel column combine + solve ----
    const int i = i0 + ty, j = j0 + tx;
    const bool valid = (i < HH) && (j < WW);

    float contrib = 0.0f;
    if (valid) {
        float aa[8], a2[8];
#pragma unroll
        for (int dc = 0; dc < 8; ++dc) {
            float a = ((float)(j - 4 + dc) - 319.5f) * invFX;
            aa[dc] = a;
            a2[dc] = a * a;
        }
        float bc = ((float)i - 239.5f) * invFY;
        const int ebase = ty * 24 + tx;

        float n2[2][3];
#pragma unroll
        for (int k = 0; k < 2; ++k) {
            float xx = 0.f, xy = 0.f, xz = 0.f, yy = 0.f, yz = 0.f, zz = 0.f;
            float xs = 0.f, ys = 0.f, zs = 0.f;
#pragma unroll
            for (int dc = 0; dc < 8; ++dc) {
                const float* e = cs[k][ebase + dc];
                float2 p01 = *(const float2*)(e);       // S1, Sb
                float2 p23 = *(const float2*)(e + 2);   // Sbb, T1
                float  tb  = csTb[k][ebase + dc];
                zz += p01.x;  yz += p01.y;  yy += p23.x;
                zs += p23.y;  ys += tb;
                xz = fmaf(aa[dc], p01.x, xz);
                xy = fmaf(aa[dc], p01.y, xy);
                xs = fmaf(aa[dc], p23.y, xs);
                xx = fmaf(a2[dc], p01.x, xx);
            }
            float d0 = sd[k][(ty + 4) * 24 + (tx + 4)];
            solve_normal(xx, xy, xz, yy, yz, zz, xs, ys, zs,
                         aa[4], bc, d0, &n2[k][0], &n2[k][1], &n2[k][2]);
        }
        contrib = fabsf(n2[0][0] - n2[1][0])
                + fabsf(n2[0][1] - n2[1][1])
                + fabsf(n2[0][2] - n2[1][2]);
    }

    // ---- reduce: wave shuffle -> LDS -> one atomic/block; last block finalizes ----
    float v = contrib;
#pragma unroll
    for (int off = 32; off > 0; off >>= 1) v += __shfl_down(v, off, 64);
    __shared__ float wsum[4];
    int wid = tid >> 6, lane = tid & 63;
    if (lane == 0) wsum[wid] = v;
    __syncthreads();
    if (tid == 0) {
        double bs = (double)wsum[0] + (double)wsum[1] + (double)wsum[2] + (double)wsum[3];
        atomicAdd(acc, bs);
        __threadfence();
        unsigned int old = atomicAdd(cnt, 1u);
        if (old == NBLK - 1) {
            double total = atomicAdd(acc, 0.0);   // coherent device-scope read
            out[0] = (float)(total * (1.0 / 7345944.0));  // mean over B*3*H*W
        }
    }
}

extern "C" void kernel_launch(void* const* d_in, const int* in_sizes, int n_in,
                              void* d_out, int out_size, void* d_ws, size_t ws_size,
                              hipStream_t stream)
{
    const float* pred = (const float*)d_in[0];
    const float* gt   = (const float*)d_in[1];
    float* out = (float*)d_out;
    double* acc = (double*)d_ws;
    unsigned int* cnt = (unsigned int*)((char*)d_ws + 8);

    hipMemsetAsync(d_ws, 0, 16, stream);

    dim3 grid((WW + 15) / 16, (HH + 15) / 16, BATCH);  // 40 x 30 x 8
    dim3 block(16, 16);
    ppal_main<<<grid, block, 0, stream>>>(pred, gt, acc, cnt, out);
}

// Round 4
// 104.764 us; speedup vs baseline: 2.9787x; 2.9787x over previous
//
#include <hip/hip_runtime.h>

#define HH 479
#define WW 639
#define BATCH 8
#define NACC 64   // accumulator slots (reduce same-line atomic contention)

// Separable moments per (output-row i, window-col c):
//   S1=SUM d^2, Sb=SUM b d^2, Sbb=SUM b^2 d^2, T1=SUM d, Tb=SUM b d  (8 rows)
// Per pixel combine over 8 window-cols with weights {1, a, a^2}.
// Solve: adjugate*rhs (m) in f64 (cancellation-prone), finish in f32.
// Det-free flip: final = -sign(dot(m, xyz)) * m/|m|.
// Retirement: fire-and-forget atomicAdd into acc[block%64], finalize kernel
// sums them. NO fence / counter-readback — round 2/3 showed that serializes
// block retirement device-wide (~41 us/block wall vs <10 us compute).

__device__ __forceinline__ void solve_normal(
    float xx, float xy, float xz, float yy, float yz, float zz,
    float xs, float ys, float zs,
    float a_c, float b_c, float d0,
    float* nx, float* ny, float* nz)
{
    const double EPSV = 1e-6;
    double p = (double)xx + EPSV, q = (double)xy, r = (double)xz;
    double s = (double)yy + EPSV, t = (double)yz, u = (double)zz + EPSV;
    double c00 = s * u - t * t;
    double c01 = r * t - q * u;
    double c02 = q * t - r * s;
    double c11 = p * u - r * r;
    double c12 = q * r - p * t;
    double c22 = p * s - q * q;
    double m0 = c00 * (double)xs + c01 * (double)ys + c02 * (double)zs;
    double m1 = c01 * (double)xs + c11 * (double)ys + c12 * (double)zs;
    double m2 = c02 * (double)xs + c12 * (double)ys + c22 * (double)zs;
    float f0 = (float)m0, f1 = (float)m1, f2 = (float)m2;
    float g = fmaf(f0, a_c, fmaf(f1, b_c, f2));
    float inv = rsqrtf(fmaf(f0, f0, fmaf(f1, f1, f2 * f2)));
    if (g > 0.0f) inv = -inv;
    if (!(d0 > 0.0f)) inv = 0.0f;                    // where(depth>0, n, 0)
    *nx = f0 * inv; *ny = f1 * inv; *nz = f2 * inv;
}

__global__ __launch_bounds__(256, 4)
void ppal_main(const float* __restrict__ pred, const float* __restrict__ gt,
               double* __restrict__ acc)
{
    const int tx = threadIdx.x;        // 0..15
    const int ty = threadIdx.y;        // 0..15
    const int tid = ty * 16 + tx;
    const int j0 = blockIdx.x * 16;
    const int i0 = blockIdx.y * 16;
    const int b  = blockIdx.z;

    const float invFX = 1.0f / 518.857f;
    const float invFY = 1.0f / 519.469f;

    // depth tile rows i0-4..i0+18 (23), cols j0-4..j0+18 (23); stride 24
    __shared__ float sd[2][23 * 24];
    // column sums, entry e=i*24+c: dw{0..4}={S1,Sb,Sbb,T1,Tb}, dw5 pad
    // stride 6 dw: banks 6t+{0,1,2,3,4} mod 32 -> conflict-free b64/b32 mix
    __shared__ float cs[2][384][6];

    const float* src0 = pred + (size_t)b * (HH * WW);
    const float* src1 = gt   + (size_t)b * (HH * WW);
    for (int idx = tid; idx < 23 * 24; idx += 256) {
        int lr = idx / 24, lc = idx - lr * 24;
        int r = i0 - 4 + lr, c = j0 - 4 + lc;
        bool ok = (lc < 23) && (r >= 0) && (r < HH) && (c >= 0) && (c < WW);
        int off = r * WW + c;
        sd[0][idx] = ok ? src0[off] : 0.0f;
        sd[1][idx] = ok ? src1[off] : 0.0f;
    }
    __syncthreads();

    // ---- stage 1: row reductions; tasks t: i=t/24, c=t%24 (consecutive LDS) ----
    for (int t = tid; t < 384; t += 256) {
        int i = t / 24;
        int c = t - i * 24;
        float S1[2] = {0.f, 0.f}, Sb[2] = {0.f, 0.f}, Sbb[2] = {0.f, 0.f};
        float T1[2] = {0.f, 0.f}, Tb[2] = {0.f, 0.f};
#pragma unroll
        for (int dr = 0; dr < 8; ++dr) {
            float bv = ((float)(i0 + i - 4 + dr) - 239.5f) * invFY;
#pragma unroll
            for (int k = 0; k < 2; ++k) {
                float d  = sd[k][(i + dr) * 24 + c];
                float bd = bv * d;
                T1[k] += d;
                Tb[k] += bd;
                S1[k]  = fmaf(d,  d,  S1[k]);
                Sb[k]  = fmaf(bd, d,  Sb[k]);
                Sbb[k] = fmaf(bd, bd, Sbb[k]);
            }
        }
#pragma unroll
        for (int k = 0; k < 2; ++k) {
            float* e = cs[k][t];
            *(float2*)(e)     = make_float2(S1[k], Sb[k]);
            *(float2*)(e + 2) = make_float2(Sbb[k], T1[k]);
            e[4] = Tb[k];
        }
    }
    __syncthreads();

    // ---- stage 2: per-pixel column combine + solve ----
    const int i = i0 + ty, j = j0 + tx;
    const bool valid = (i < HH) && (j < WW);

    float contrib = 0.0f;
    if (valid) {
        float aa[8], a2[8];
#pragma unroll
        for (int dc = 0; dc < 8; ++dc) {
            float a = ((float)(j - 4 + dc) - 319.5f) * invFX;
            aa[dc] = a;
            a2[dc] = a * a;
        }
        float bc = ((float)i - 239.5f) * invFY;
        const int ebase = ty * 24 + tx;

        float n2[2][3];
#pragma unroll
        for (int k = 0; k < 2; ++k) {
            float xx = 0.f, xy = 0.f, xz = 0.f, yy = 0.f, yz = 0.f, zz = 0.f;
            float xs = 0.f, ys = 0.f, zs = 0.f;
#pragma unroll
            for (int dc = 0; dc < 8; ++dc) {
                const float* e = cs[k][ebase + dc];
                float2 p01 = *(const float2*)(e);       // S1, Sb
                float2 p23 = *(const float2*)(e + 2);   // Sbb, T1
                float  tb  = e[4];                      // Tb
                zz += p01.x;  yz += p01.y;  yy += p23.x;
                zs += p23.y;  ys += tb;
                xz = fmaf(aa[dc], p01.x, xz);
                xy = fmaf(aa[dc], p01.y, xy);
                xs = fmaf(aa[dc], p23.y, xs);
                xx = fmaf(a2[dc], p01.x, xx);
            }
            float d0 = sd[k][(ty + 4) * 24 + (tx + 4)];
            solve_normal(xx, xy, xz, yy, yz, zz, xs, ys, zs,
                         aa[4], bc, d0, &n2[k][0], &n2[k][1], &n2[k][2]);
        }
        contrib = fabsf(n2[0][0] - n2[1][0])
                + fabsf(n2[0][1] - n2[1][1])
                + fabsf(n2[0][2] - n2[1][2]);
    }

    // ---- reduce: wave shuffle -> LDS -> ONE fire-and-forget atomic/block ----
    float v = contrib;
#pragma unroll
    for (int off = 32; off > 0; off >>= 1) v += __shfl_down(v, off, 64);
    __shared__ float wsum[4];
    int wid = tid >> 6, lane = tid & 63;
    if (lane == 0) wsum[wid] = v;
    __syncthreads();
    if (tid == 0) {
        double bs = (double)wsum[0] + (double)wsum[1] + (double)wsum[2] + (double)wsum[3];
        int slot = (blockIdx.x + 40 * blockIdx.y + 1200 * blockIdx.z) & (NACC - 1);
        atomicAdd(&acc[slot], bs);
    }
}

__global__ void ppal_finalize(const double* __restrict__ acc, float* __restrict__ out)
{
    int lane = threadIdx.x;            // 64 threads
    double v = acc[lane];
#pragma unroll
    for (int off = 32; off > 0; off >>= 1) v += __shfl_down(v, off, 64);
    if (lane == 0)
        out[0] = (float)(v * (1.0 / 7345944.0));  // mean over B*3*H*W
}

extern "C" void kernel_launch(void* const* d_in, const int* in_sizes, int n_in,
                              void* d_out, int out_size, void* d_ws, size_t ws_size,
                              hipStream_t stream)
{
    const float* pred = (const float*)d_in[0];
    const float* gt   = (const float*)d_in[1];
    float* out  = (float*)d_out;
    double* acc = (double*)d_ws;

    hipMemsetAsync(acc, 0, NACC * sizeof(double), stream);

    dim3 grid((WW + 15) / 16, (HH + 15) / 16, BATCH);  // 40 x 30 x 8 = 9600
    dim3 block(16, 16);
    ppal_main<<<grid, block, 0, stream>>>(pred, gt, acc);
    ppal_finalize<<<1, 64, 0, stream>>>(acc, out);
}